// Round 10
// baseline (49.878 us; speedup 1.0000x reference)
//
#include <hip/hip_runtime.h>

// EVI fused kernel, round 10: float4 voxel-group per thread, batched wide loads.
// R9 analysis: at 5.64 TB/s fabric (90% of the m13 float4-copy ceiling), the
// remaining gap may be load WIDTH: m13's 10.2 B/cyc/CU was measured with
// dwordx4; R8/R9 issue dwordx2. This kernel moves the same bytes with half
// the VMEM instructions: one thread = one float4 voxel-group (4 voxels),
// all 64 channels, loaded in 4 fenced batches of 16 x dwordx4 (64 VGPR live
// per batch - honestly fits; nothing live across the epilogue -> no R4/R5
// spill). Stores: 64 x dwordx4 nt per thread.
// - 131072 threads -> 512 blocks (R8/R9 effective occupancy was ~6 waves/CU,
//   so 8 waves/CU grid supply is not binding).
// - No cross-lane ops, no scan duplication (4 voxels scanned in-register).
// - Non-temporal stores keep `out` from evicting x out of the 256 MB L3.

constexpr int kInCh    = 64;
constexpr int kCls     = 4;
constexpr int kProto   = 20;
constexpr long kSpatial = 64L * 64L * 64L;            // 262144, D contiguous
constexpr int kVec     = 4;                            // voxels per thread
constexpr int kGrpPerBatch = (int)(kSpatial / kVec);   // 65536
constexpr int kBatch   = 16;                           // loads per fenced batch

typedef float f32x4 __attribute__((ext_vector_type(4)));

__global__ __launch_bounds__(256) void evi_fused_kernel(
    const float* __restrict__ x,
    const float* __restrict__ w_to,    // (CLS, IN_CH)
    const float* __restrict__ b_to,    // (CLS,)
    const float* __restrict__ w_from,  // (IN_CH, CLS)
    const float* __restrict__ b_from,  // (IN_CH,)
    const float* __restrict__ Wm,      // (PROTO, CLS)
    const float* __restrict__ BETA,    // (PROTO, CLS)
    const float* __restrict__ alpha,   // (PROTO, 1)
    const float* __restrict__ gamma,   // (PROTO, 1)
    float* __restrict__ out)
{
    __shared__ float s_wt[kCls * kInCh];   // w_to[o][c]
    __shared__ float s_wf[kInCh * kCls];   // w_from[i][c]
    __shared__ float s_bf[kInCh];
    __shared__ float s_bto[kCls];
    __shared__ float s_W[kProto][kCls];
    __shared__ float s_U[kProto][kCls];
    __shared__ float s_ap[kProto];
    __shared__ float s_g2[kProto];

    const int t = threadIdx.x;

    // ---- stage weights / per-proto params into LDS (once per block) ----
    s_wt[t] = w_to[t];
    s_wf[t] = w_from[t];
    if (t < kInCh) s_bf[t] = b_from[t];
    if (t < kCls)  s_bto[t] = b_to[t];
    if (t < kProto) {
        float bsq[kCls];
        float sum = 0.f;
        #pragma unroll
        for (int c = 0; c < kCls; ++c) {
            const float bb = BETA[t * kCls + c];
            bsq[c] = bb * bb;
            sum += bsq[c];
        }
        const float inv = 1.0f / sum;
        #pragma unroll
        for (int c = 0; c < kCls; ++c) {
            s_U[t][c] = bsq[c] * inv;
            s_W[t][c] = Wm[t * kCls + c];
        }
        s_ap[t] = 0.99f / (1.0f + expf(-alpha[t]));
        const float g = gamma[t];
        s_g2[t] = g * g;
    }
    __syncthreads();

    // ---- one float4 voxel-group per thread, all 64 channels ----
    const int tid = blockIdx.x * blockDim.x + t;      // [0, 131072)
    const int b   = tid >> 16;                        // tid / 65536
    const int r   = tid & (kGrpPerBatch - 1);
    const size_t base = (size_t)b * kInCh * kSpatial + (size_t)r * kVec;

    float ev[kCls][kVec];
    #pragma unroll
    for (int o = 0; o < kCls; ++o)
        #pragma unroll
        for (int v = 0; v < kVec; ++v) ev[o][v] = s_bto[o];

    // ---- 4 fenced batches: 16 x dwordx4 loads issued back-to-back, then consume ----
    #pragma unroll
    for (int bb = 0; bb < kInCh / kBatch; ++bb) {
        const int cb = bb * kBatch;
        f32x4 xv[kBatch];
        #pragma unroll
        for (int j = 0; j < kBatch; ++j)
            xv[j] = *reinterpret_cast<const f32x4*>(x + base + (size_t)(cb + j) * kSpatial);
        __builtin_amdgcn_sched_barrier(0);   // all 16 VMEM issued before consumption

        #pragma unroll
        for (int j = 0; j < kBatch; ++j) {
            const int c = cb + j;
            #pragma unroll
            for (int o = 0; o < kCls; ++o) {
                const float w = s_wt[o * kInCh + c];
                ev[o][0] += xv[j].x * w;
                ev[o][1] += xv[j].y * w;
                ev[o][2] += xv[j].z * w;
                ev[o][3] += xv[j].w * w;
            }
        }
    }

    // ---- 20-proto evidence scan (4 voxels, all in registers, static indices) ----
    float mkc[kCls][kVec];
    float mk5[kVec];
    #pragma unroll
    for (int v = 0; v < kVec; ++v) {
        mk5[v] = 1.0f;
        #pragma unroll
        for (int c = 0; c < kCls; ++c) mkc[c][v] = 0.0f;
    }

    for (int k = 0; k < kProto; ++k) {
        const float ap = s_ap[k];
        const float g2 = s_g2[k];
        float Wk[kCls], Uk[kCls];
        #pragma unroll
        for (int c = 0; c < kCls; ++c) { Wk[c] = s_W[k][c]; Uk[c] = s_U[k][c]; }
        #pragma unroll
        for (int v = 0; v < kVec; ++v) {
            float d = 0.0f;
            #pragma unroll
            for (int c = 0; c < kCls; ++c) {
                const float df = ev[c][v] - Wk[c];
                d += df * df;
            }
            d *= 0.5f;
            const float s  = ap * __expf(-g2 * d);
            const float m5 = 1.0f - s;
            const float old5 = mk5[v];
            #pragma unroll
            for (int c = 0; c < kCls; ++c) {
                const float mc = Uk[c] * s;
                mkc[c][v] = mkc[c][v] * (mc + m5) + mc * old5;
            }
            mk5[v] = old5 * m5;
        }
    }

    // ---- normalize: evid[c] = (mkc[c] + mk5) / K ----
    float evid[kCls][kVec];
    #pragma unroll
    for (int v = 0; v < kVec; ++v) {
        float K = mk5[v];
        #pragma unroll
        for (int c = 0; c < kCls; ++c) K += mkc[c][v];
        const float inv = 1.0f / K;
        #pragma unroll
        for (int c = 0; c < kCls; ++c) evid[c][v] = (mkc[c][v] + mk5[v]) * inv;
    }

    // ---- out = w_from . evid + b_from (64 channels, nt dwordx4 stores) ----
    #pragma unroll
    for (int o = 0; o < kInCh; ++o) {
        const float w0 = s_wf[o * kCls + 0];
        const float w1 = s_wf[o * kCls + 1];
        const float w2 = s_wf[o * kCls + 2];
        const float w3 = s_wf[o * kCls + 3];
        const float bo = s_bf[o];
        f32x4 acc;
        acc.x = bo + evid[0][0]*w0 + evid[1][0]*w1 + evid[2][0]*w2 + evid[3][0]*w3;
        acc.y = bo + evid[0][1]*w0 + evid[1][1]*w1 + evid[2][1]*w2 + evid[3][1]*w3;
        acc.z = bo + evid[0][2]*w0 + evid[1][2]*w1 + evid[2][2]*w2 + evid[3][2]*w3;
        acc.w = bo + evid[0][3]*w0 + evid[1][3]*w1 + evid[2][3]*w2 + evid[3][3]*w3;
        __builtin_nontemporal_store(acc, reinterpret_cast<f32x4*>(out + base + (size_t)o * kSpatial));
    }
}

extern "C" void kernel_launch(void* const* d_in, const int* in_sizes, int n_in,
                              void* d_out, int out_size, void* d_ws, size_t ws_size,
                              hipStream_t stream) {
    const float* x      = (const float*)d_in[0];
    const float* w_to   = (const float*)d_in[1];
    const float* b_to   = (const float*)d_in[2];
    const float* w_from = (const float*)d_in[3];
    const float* b_from = (const float*)d_in[4];
    const float* Wm     = (const float*)d_in[5];
    const float* BETA   = (const float*)d_in[6];
    const float* alpha  = (const float*)d_in[7];
    const float* gamma  = (const float*)d_in[8];
    float* out = (float*)d_out;

    // 131072 voxel-groups -> 131072 threads -> 512 blocks
    const int block = 256;
    const int grid  = 512;
    evi_fused_kernel<<<grid, block, 0, stream>>>(x, w_to, b_to, w_from, b_from,
                                                 Wm, BETA, alpha, gamma, out);
}

// Round 11
// 47.377 us; speedup vs baseline: 1.0528x; 1.0528x over previous
//
#include <hip/hip_runtime.h>

// EVI fused kernel, FINAL (revert to round-9 best: 47.0 us, 5.64 TB/s fabric =
// 90% of the measured 6.29 TB/s copy ceiling; mixed-R/W roofline).
// Structure: one float2 voxel-pair per thread, all 64 channels.
// - 512 B contiguous per channel per wave-load (64 lanes x 8 B) - measured
//   optimum (128B: 57.8us, 256B: 52.4us, 512B: 47.0us, 1024B@512blk: 49.9us).
// - All 64 loads issued back-to-back, fenced with sched_barrier(0) so the
//   scheduler cannot sink loads below consumption (+5% vs unfenced).
// - No cross-lane ops (phantom 16KB LDS + bank conflicts traced to __shfl).
// - No in-thread multi-generation pipelining (spills: 650 MB scratch, R4/R5).
// - Non-temporal stores keep `out` from evicting x out of the 256 MB L3
//   (FETCH_SIZE 65.7 MB < 134 MB input proves cross-replay L3 residency).
// - 262144 threads -> 1024 blocks; VGPR 92, zero spill, zero conflicts.

constexpr int kInCh    = 64;
constexpr int kCls     = 4;
constexpr int kProto   = 20;
constexpr long kSpatial = 64L * 64L * 64L;   // 262144, D contiguous
constexpr int kPairsPerBatch = (int)(kSpatial / 2);   // 131072 float2 pairs

typedef float f32x2 __attribute__((ext_vector_type(2)));

__global__ __launch_bounds__(256) void evi_fused_kernel(
    const float* __restrict__ x,
    const float* __restrict__ w_to,    // (CLS, IN_CH)
    const float* __restrict__ b_to,    // (CLS,)
    const float* __restrict__ w_from,  // (IN_CH, CLS)
    const float* __restrict__ b_from,  // (IN_CH,)
    const float* __restrict__ Wm,      // (PROTO, CLS)
    const float* __restrict__ BETA,    // (PROTO, CLS)
    const float* __restrict__ alpha,   // (PROTO, 1)
    const float* __restrict__ gamma,   // (PROTO, 1)
    float* __restrict__ out)
{
    __shared__ float s_wt[kCls * kInCh];   // w_to[o][c]
    __shared__ float s_wf[kInCh * kCls];   // w_from[i][c]
    __shared__ float s_bf[kInCh];
    __shared__ float s_bto[kCls];
    __shared__ float s_W[kProto][kCls];
    __shared__ float s_U[kProto][kCls];
    __shared__ float s_ap[kProto];
    __shared__ float s_g2[kProto];

    const int t = threadIdx.x;

    // ---- stage weights / per-proto params into LDS (once per block) ----
    s_wt[t] = w_to[t];
    s_wf[t] = w_from[t];
    if (t < kInCh) s_bf[t] = b_from[t];
    if (t < kCls)  s_bto[t] = b_to[t];
    if (t < kProto) {
        float bsq[kCls];
        float sum = 0.f;
        #pragma unroll
        for (int c = 0; c < kCls; ++c) {
            const float bb = BETA[t * kCls + c];
            bsq[c] = bb * bb;
            sum += bsq[c];
        }
        const float inv = 1.0f / sum;
        #pragma unroll
        for (int c = 0; c < kCls; ++c) {
            s_U[t][c] = bsq[c] * inv;
            s_W[t][c] = Wm[t * kCls + c];
        }
        s_ap[t] = 0.99f / (1.0f + expf(-alpha[t]));
        const float g = gamma[t];
        s_g2[t] = g * g;
    }
    __syncthreads();

    // ---- one float2 voxel-pair per thread, all 64 channels ----
    const int tid = blockIdx.x * blockDim.x + t;      // [0, 262144)
    const int b   = tid >> 17;                        // tid / 131072
    const int r   = tid & (kPairsPerBatch - 1);
    const size_t base = (size_t)b * kInCh * kSpatial + (size_t)r * 2;

    // ---- issue ALL 64 loads back-to-back; fence so nothing sinks below ----
    f32x2 xv[kInCh];
    #pragma unroll
    for (int c = 0; c < kInCh; ++c)
        xv[c] = *reinterpret_cast<const f32x2*>(x + base + (size_t)c * kSpatial);
    __builtin_amdgcn_sched_barrier(0);   // all 64 VMEM issued before any VALU below

    // ---- ev = w_to . x + b_to (2 voxels); consumes xv in issue order ----
    float ev[kCls][2];
    #pragma unroll
    for (int o = 0; o < kCls; ++o) {
        ev[o][0] = s_bto[o];
        ev[o][1] = s_bto[o];
    }
    #pragma unroll
    for (int c = 0; c < kInCh; ++c) {
        #pragma unroll
        for (int o = 0; o < kCls; ++o) {
            const float w = s_wt[o * kInCh + c];
            ev[o][0] += xv[c].x * w;
            ev[o][1] += xv[c].y * w;
        }
    }

    // ---- 20-proto evidence scan (2 voxels, all in registers, static indices) ----
    float mkc[kCls][2];
    float mk5[2] = {1.0f, 1.0f};
    #pragma unroll
    for (int c = 0; c < kCls; ++c) { mkc[c][0] = 0.0f; mkc[c][1] = 0.0f; }

    for (int k = 0; k < kProto; ++k) {
        const float ap = s_ap[k];
        const float g2 = s_g2[k];
        float Wk[kCls], Uk[kCls];
        #pragma unroll
        for (int c = 0; c < kCls; ++c) { Wk[c] = s_W[k][c]; Uk[c] = s_U[k][c]; }
        #pragma unroll
        for (int v = 0; v < 2; ++v) {
            float d = 0.0f;
            #pragma unroll
            for (int c = 0; c < kCls; ++c) {
                const float df = ev[c][v] - Wk[c];
                d += df * df;
            }
            d *= 0.5f;
            const float s  = ap * __expf(-g2 * d);
            const float m5 = 1.0f - s;
            const float old5 = mk5[v];
            #pragma unroll
            for (int c = 0; c < kCls; ++c) {
                const float mc = Uk[c] * s;
                mkc[c][v] = mkc[c][v] * (mc + m5) + mc * old5;
            }
            mk5[v] = old5 * m5;
        }
    }

    // ---- normalize: evid[c] = (mkc[c] + mk5) / K ----
    float evid[kCls][2];
    #pragma unroll
    for (int v = 0; v < 2; ++v) {
        float K = mk5[v];
        #pragma unroll
        for (int c = 0; c < kCls; ++c) K += mkc[c][v];
        const float inv = 1.0f / K;
        #pragma unroll
        for (int c = 0; c < kCls; ++c) evid[c][v] = (mkc[c][v] + mk5[v]) * inv;
    }

    // ---- out = w_from . evid + b_from (64 channels, nt float2 stores) ----
    #pragma unroll
    for (int o = 0; o < kInCh; ++o) {
        const float w0 = s_wf[o * kCls + 0];
        const float w1 = s_wf[o * kCls + 1];
        const float w2 = s_wf[o * kCls + 2];
        const float w3 = s_wf[o * kCls + 3];
        const float bo = s_bf[o];
        f32x2 acc;
        acc.x = bo + evid[0][0]*w0 + evid[1][0]*w1 + evid[2][0]*w2 + evid[3][0]*w3;
        acc.y = bo + evid[0][1]*w0 + evid[1][1]*w1 + evid[2][1]*w2 + evid[3][1]*w3;
        __builtin_nontemporal_store(acc, reinterpret_cast<f32x2*>(out + base + (size_t)o * kSpatial));
    }
}

extern "C" void kernel_launch(void* const* d_in, const int* in_sizes, int n_in,
                              void* d_out, int out_size, void* d_ws, size_t ws_size,
                              hipStream_t stream) {
    const float* x      = (const float*)d_in[0];
    const float* w_to   = (const float*)d_in[1];
    const float* b_to   = (const float*)d_in[2];
    const float* w_from = (const float*)d_in[3];
    const float* b_from = (const float*)d_in[4];
    const float* Wm     = (const float*)d_in[5];
    const float* BETA   = (const float*)d_in[6];
    const float* alpha  = (const float*)d_in[7];
    const float* gamma  = (const float*)d_in[8];
    float* out = (float*)d_out;

    // 262144 voxel-pairs -> 262144 threads -> 1024 blocks
    const int block = 256;
    const int grid  = 1024;
    evi_fused_kernel<<<grid, block, 0, stream>>>(x, w_to, b_to, w_from, b_from,
                                                 Wm, BETA, alpha, gamma, out);
}